// Round 2
// baseline (573.219 us; speedup 1.0000x reference)
//
#include <hip/hip_runtime.h>
#include <math.h>

#define NN   10000          // nodes
#define NE   160000         // raw edges
#define NET  (NE + NN)      // edges + self loops = 170000
#define FIN  70
#define KP   72             // FIN padded to 16B multiple
#define HIDC 256
#define NH   4
#define D1   1024           // NH*HIDC
#define SLOPE 0.2f

// ---------------- CSR build ----------------
__global__ void k_hist(const int* __restrict__ ei, int* __restrict__ counts) {
    int e = blockIdx.x * 256 + threadIdx.x;
    if (e >= NET) return;
    int dst = (e < NE) ? ei[NE + e] : (e - NE);
    atomicAdd(&counts[dst], 1);
}

__global__ __launch_bounds__(1024) void k_scan(const int* __restrict__ counts,
                                               int* __restrict__ indptr,
                                               int* __restrict__ cursor) {
    __shared__ int ls[1024];
    int t = threadIdx.x;
    int c[10];
    int base = t * 10;
    int lsum = 0;
#pragma unroll
    for (int i = 0; i < 10; i++) {
        int j = base + i;
        c[i] = (j < NN) ? counts[j] : 0;
        lsum += c[i];
    }
    ls[t] = lsum;
    __syncthreads();
    for (int off = 1; off < 1024; off <<= 1) {
        int v = (t >= off) ? ls[t - off] : 0;
        __syncthreads();
        ls[t] += v;
        __syncthreads();
    }
    int excl = ls[t] - lsum;
#pragma unroll
    for (int i = 0; i < 10; i++) {
        int j = base + i;
        if (j < NN) { indptr[j] = excl; cursor[j] = excl; excl += c[i]; }
    }
    if (t == 1023) indptr[NN] = ls[1023];
}

__global__ void k_scatter(const int* __restrict__ ei, int* __restrict__ cursor,
                          int* __restrict__ ssrc) {
    int e = blockIdx.x * 256 + threadIdx.x;
    if (e >= NET) return;
    int src, dst;
    if (e < NE) { src = ei[e]; dst = ei[NE + e]; }
    else        { src = e - NE; dst = src; }
    int pos = atomicAdd(&cursor[dst], 1);
    ssrc[pos] = src;
}

// ---------------- precompute was1/wad1: was[h][k] = sum_c W1[k, h*256+c] * att_src1[h,c] ----------------
__global__ __launch_bounds__(256) void k_prep1(const float* __restrict__ W1,
                                               const float* __restrict__ asrc,
                                               const float* __restrict__ adst,
                                               float* __restrict__ was,
                                               float* __restrict__ wad) {
    int k = blockIdx.x, t = threadIdx.x;
    __shared__ float rs[256], rd[256];
#pragma unroll
    for (int h = 0; h < NH; h++) {
        float wv = W1[(size_t)k * D1 + h * 256 + t];
        rs[t] = wv * asrc[h * 256 + t];
        rd[t] = wv * adst[h * 256 + t];
        __syncthreads();
        for (int off = 128; off > 0; off >>= 1) {
            if (t < off) { rs[t] += rs[t + off]; rd[t] += rd[t + off]; }
            __syncthreads();
        }
        if (t == 0) { was[h * FIN + k] = rs[0]; wad[h * FIN + k] = rd[0]; }
        __syncthreads();
    }
}

// ---------------- per-node attention logits from x: as1[n][h] = x[n] . was[h] ----------------
__global__ __launch_bounds__(64) void k_att_x(const float* __restrict__ x,
                                              const float* __restrict__ was,
                                              const float* __restrict__ wad,
                                              float* __restrict__ asn,
                                              float* __restrict__ adn) {
    __shared__ float xs[64][71];
    int t = threadIdx.x;
    int n0 = blockIdx.x * 64;
    for (int i = t; i < 64 * FIN; i += 64) {
        int r = i / FIN, k = i % FIN;
        int n = n0 + r;
        xs[r][k] = (n < NN) ? x[(size_t)n * FIN + k] : 0.f;
    }
    __syncthreads();
    int n = n0 + t;
    if (n >= NN) return;
    float a[NH] = {}, d[NH] = {};
    for (int k = 0; k < FIN; k++) {
        float xv = xs[t][k];
#pragma unroll
        for (int h = 0; h < NH; h++) {
            a[h] += xv * was[h * FIN + k];
            d[h] += xv * wad[h * FIN + k];
        }
    }
#pragma unroll
    for (int h = 0; h < NH; h++) { asn[n * NH + h] = a[h]; adn[n * NH + h] = d[h]; }
}

// ---------------- per-node attention coefficients from a feature buffer (layer 2) ----------------
__global__ __launch_bounds__(256) void k_att_h(const float* __restrict__ hbuf,
                                               const float* __restrict__ asrc,
                                               const float* __restrict__ adst,
                                               float* __restrict__ asn,
                                               float* __restrict__ adn) {
    int n = blockIdx.x, t = threadIdx.x;
    __shared__ float rs[256], rd[256];
    float v = hbuf[(size_t)n * HIDC + t];
    rs[t] = v * asrc[t];
    rd[t] = v * adst[t];
    __syncthreads();
    for (int off = 128; off > 0; off >>= 1) {
        if (t < off) { rs[t] += rs[t + off]; rd[t] += rd[t + off]; }
        __syncthreads();
    }
    if (t == 0) { asn[n] = rs[0]; adn[n] = rd[0]; }
}

// ---------------- per-dst-node segment softmax (1 wave/node) ----------------
template <int H>
__global__ __launch_bounds__(64) void k_edge_softmax(const int* __restrict__ indptr,
                                                     const int* __restrict__ ssrc,
                                                     const float* __restrict__ as,
                                                     const float* __restrict__ ad,
                                                     float* __restrict__ alpha) {
    int d = blockIdx.x;
    int lane = threadIdx.x;
    int beg = indptr[d], end = indptr[d + 1];
    float adv[H], m[H], sum[H];
#pragma unroll
    for (int h = 0; h < H; h++) { adv[h] = ad[d * H + h]; m[h] = -1e30f; sum[h] = 0.f; }
    for (int i = beg + lane; i < end; i += 64) {
        int s = ssrc[i];
#pragma unroll
        for (int h = 0; h < H; h++) {
            float e = as[s * H + h] + adv[h];
            e = (e > 0.f) ? e : SLOPE * e;
            m[h] = fmaxf(m[h], e);
        }
    }
#pragma unroll
    for (int h = 0; h < H; h++)
        for (int off = 32; off > 0; off >>= 1)
            m[h] = fmaxf(m[h], __shfl_xor(m[h], off));
    for (int i = beg + lane; i < end; i += 64) {
        int s = ssrc[i];
#pragma unroll
        for (int h = 0; h < H; h++) {
            float e = as[s * H + h] + adv[h];
            e = (e > 0.f) ? e : SLOPE * e;
            float ex = expf(e - m[h]);
            alpha[(size_t)i * H + h] = ex;
            sum[h] += ex;
        }
    }
#pragma unroll
    for (int h = 0; h < H; h++)
        for (int off = 32; off > 0; off >>= 1)
            sum[h] += __shfl_xor(sum[h], off);
    float inv[H];
#pragma unroll
    for (int h = 0; h < H; h++) inv[h] = 1.0f / (sum[h] + 1e-16f);
    for (int i = beg + lane; i < end; i += 64)
#pragma unroll
        for (int h = 0; h < H; h++)
            alpha[(size_t)i * H + h] *= inv[h];
}

// ---------------- layer-1 aggregation in INPUT space: aggX[d][h][k] = sum alpha1[e][h]*x[src][k] ----------------
__global__ __launch_bounds__(64) void k_aggX(const int* __restrict__ indptr,
                                             const int* __restrict__ ssrc,
                                             const float* __restrict__ alpha1,
                                             const float* __restrict__ x,
                                             float* __restrict__ aggX) {
    int d = blockIdx.x, t = threadIdx.x;
    int beg = indptr[d], end = indptr[d + 1];
    float ac[NH][2] = {};
    for (int i = beg; i < end; i++) {
        int s = ssrc[i];
        float4 al = *(const float4*)&alpha1[(size_t)i * 4];
        float xv0 = x[(size_t)s * FIN + t];
        float xv1 = (t < FIN - 64) ? x[(size_t)s * FIN + 64 + t] : 0.f;
        ac[0][0] += al.x * xv0; ac[0][1] += al.x * xv1;
        ac[1][0] += al.y * xv0; ac[1][1] += al.y * xv1;
        ac[2][0] += al.z * xv0; ac[2][1] += al.z * xv1;
        ac[3][0] += al.w * xv0; ac[3][1] += al.w * xv1;
    }
#pragma unroll
    for (int h = 0; h < NH; h++) {
        aggX[((size_t)d * NH + h) * KP + t] = ac[h][0];
        if (t < FIN - 64) aggX[((size_t)d * NH + h) * KP + 64 + t] = ac[h][1];
    }
}

// ---------------- layer-1 GEMM (post-aggregation): x2[d][h*256+c] = relu(aggX[d][h] . W1[:,h*256+c] + b1) ----------------
// grid (ceil(NN/32), 2, 4); thread: tx=t&15 -> 8 cols, ty=t>>4 -> 2 rows
__global__ __launch_bounds__(256) void k_gemm_l1(const float* __restrict__ aggX,
                                                 const float* __restrict__ W1,
                                                 const float* __restrict__ b1,
                                                 float* __restrict__ x2) {
    int t = threadIdx.x;
    int tx = t & 15, ty = t >> 4;
    int n0 = blockIdx.x * 32;
    int h  = blockIdx.z;
    int ccol = h * 256 + blockIdx.y * 128 + tx * 8;
    int r0 = n0 + ty * 2, r1 = r0 + 1;
    int cr0 = (r0 < NN) ? r0 : NN - 1;
    int cr1 = (r1 < NN) ? r1 : NN - 1;
    const float* A0 = aggX + ((size_t)cr0 * NH + h) * KP;
    const float* A1 = aggX + ((size_t)cr1 * NH + h) * KP;
    float acc0[8] = {}, acc1[8] = {};
    for (int k0 = 0; k0 <= 64; k0 += 4) {
        float4 a0 = *(const float4*)(A0 + k0);
        float4 a1 = *(const float4*)(A1 + k0);
        const float* wp = W1 + (size_t)k0 * D1 + ccol;
#pragma unroll
        for (int j = 0; j < 4; j++) {
            float4 w0 = *(const float4*)(wp + (size_t)j * D1);
            float4 w1 = *(const float4*)(wp + (size_t)j * D1 + 4);
            float av0 = ((const float*)&a0)[j];
            float av1 = ((const float*)&a1)[j];
            acc0[0] += av0 * w0.x; acc0[1] += av0 * w0.y; acc0[2] += av0 * w0.z; acc0[3] += av0 * w0.w;
            acc0[4] += av0 * w1.x; acc0[5] += av0 * w1.y; acc0[6] += av0 * w1.z; acc0[7] += av0 * w1.w;
            acc1[0] += av1 * w0.x; acc1[1] += av1 * w0.y; acc1[2] += av1 * w0.z; acc1[3] += av1 * w0.w;
            acc1[4] += av1 * w1.x; acc1[5] += av1 * w1.y; acc1[6] += av1 * w1.z; acc1[7] += av1 * w1.w;
        }
    }
    for (int k = 68; k < FIN; k++) {
        float av0 = A0[k], av1 = A1[k];
        const float* wp = W1 + (size_t)k * D1 + ccol;
        float4 w0 = *(const float4*)(wp);
        float4 w1 = *(const float4*)(wp + 4);
        acc0[0] += av0 * w0.x; acc0[1] += av0 * w0.y; acc0[2] += av0 * w0.z; acc0[3] += av0 * w0.w;
        acc0[4] += av0 * w1.x; acc0[5] += av0 * w1.y; acc0[6] += av0 * w1.z; acc0[7] += av0 * w1.w;
        acc1[0] += av1 * w0.x; acc1[1] += av1 * w0.y; acc1[2] += av1 * w0.z; acc1[3] += av1 * w0.w;
        acc1[4] += av1 * w1.x; acc1[5] += av1 * w1.y; acc1[6] += av1 * w1.z; acc1[7] += av1 * w1.w;
    }
    float4 bb0 = *(const float4*)(b1 + ccol);
    float4 bb1 = *(const float4*)(b1 + ccol + 4);
    if (r0 < NN) {
        float4 o0 = { fmaxf(acc0[0] + bb0.x, 0.f), fmaxf(acc0[1] + bb0.y, 0.f),
                      fmaxf(acc0[2] + bb0.z, 0.f), fmaxf(acc0[3] + bb0.w, 0.f) };
        float4 o1 = { fmaxf(acc0[4] + bb1.x, 0.f), fmaxf(acc0[5] + bb1.y, 0.f),
                      fmaxf(acc0[6] + bb1.z, 0.f), fmaxf(acc0[7] + bb1.w, 0.f) };
        *(float4*)(x2 + (size_t)r0 * D1 + ccol) = o0;
        *(float4*)(x2 + (size_t)r0 * D1 + ccol + 4) = o1;
    }
    if (r1 < NN) {
        float4 o0 = { fmaxf(acc1[0] + bb0.x, 0.f), fmaxf(acc1[1] + bb0.y, 0.f),
                      fmaxf(acc1[2] + bb0.z, 0.f), fmaxf(acc1[3] + bb0.w, 0.f) };
        float4 o1 = { fmaxf(acc1[4] + bb1.x, 0.f), fmaxf(acc1[5] + bb1.y, 0.f),
                      fmaxf(acc1[6] + bb1.z, 0.f), fmaxf(acc1[7] + bb1.w, 0.f) };
        *(float4*)(x2 + (size_t)r1 * D1 + ccol) = o0;
        *(float4*)(x2 + (size_t)r1 * D1 + ccol + 4) = o1;
    }
}

// ---------------- GEMM2: h2[NN x 256] = x2[NN x 1024] @ W2 ----------------
// grid (ceil(NN/32), 2); no LDS, register tiled 2 rows x 8 cols
__global__ __launch_bounds__(256) void k_gemm2(const float* __restrict__ x2,
                                               const float* __restrict__ W2,
                                               float* __restrict__ h2) {
    int t = threadIdx.x;
    int tx = t & 15, ty = t >> 4;
    int n0 = blockIdx.x * 32;
    int col0 = blockIdx.y * 128 + tx * 8;
    int r0 = n0 + ty * 2, r1 = r0 + 1;
    int cr0 = (r0 < NN) ? r0 : NN - 1;
    int cr1 = (r1 < NN) ? r1 : NN - 1;
    const float* A0 = x2 + (size_t)cr0 * D1;
    const float* A1 = x2 + (size_t)cr1 * D1;
    float acc0[8] = {}, acc1[8] = {};
#pragma unroll 2
    for (int k0 = 0; k0 < D1; k0 += 4) {
        float4 a0 = *(const float4*)(A0 + k0);
        float4 a1 = *(const float4*)(A1 + k0);
        const float* wp = W2 + (size_t)k0 * HIDC + col0;
#pragma unroll
        for (int j = 0; j < 4; j++) {
            float4 w0 = *(const float4*)(wp + (size_t)j * HIDC);
            float4 w1 = *(const float4*)(wp + (size_t)j * HIDC + 4);
            float av0 = ((const float*)&a0)[j];
            float av1 = ((const float*)&a1)[j];
            acc0[0] += av0 * w0.x; acc0[1] += av0 * w0.y; acc0[2] += av0 * w0.z; acc0[3] += av0 * w0.w;
            acc0[4] += av0 * w1.x; acc0[5] += av0 * w1.y; acc0[6] += av0 * w1.z; acc0[7] += av0 * w1.w;
            acc1[0] += av1 * w0.x; acc1[1] += av1 * w0.y; acc1[2] += av1 * w0.z; acc1[3] += av1 * w0.w;
            acc1[4] += av1 * w1.x; acc1[5] += av1 * w1.y; acc1[6] += av1 * w1.z; acc1[7] += av1 * w1.w;
        }
    }
    if (r0 < NN) {
        float4 o0 = { acc0[0], acc0[1], acc0[2], acc0[3] };
        float4 o1 = { acc0[4], acc0[5], acc0[6], acc0[7] };
        *(float4*)(h2 + (size_t)r0 * HIDC + col0) = o0;
        *(float4*)(h2 + (size_t)r0 * HIDC + col0 + 4) = o1;
    }
    if (r1 < NN) {
        float4 o0 = { acc1[0], acc1[1], acc1[2], acc1[3] };
        float4 o1 = { acc1[4], acc1[5], acc1[6], acc1[7] };
        *(float4*)(h2 + (size_t)r1 * HIDC + col0) = o0;
        *(float4*)(h2 + (size_t)r1 * HIDC + col0 + 4) = o1;
    }
}

// ---------------- layer-2 aggregation ----------------
__global__ __launch_bounds__(256) void k_aggr2(const int* __restrict__ indptr,
                                               const int* __restrict__ ssrc,
                                               const float* __restrict__ alpha,
                                               const float* __restrict__ h2,
                                               const float* __restrict__ b,
                                               float* __restrict__ x3) {
    int d = blockIdx.x, t = threadIdx.x;
    int beg = indptr[d], end = indptr[d + 1];
    float acc = 0.f;
    for (int i = beg; i < end; i++) {
        int s = ssrc[i];
        acc += alpha[i] * h2[(size_t)s * HIDC + t];
    }
    x3[(size_t)d * HIDC + t] = fmaxf(acc + b[t], 0.f);
}

// ---------------- mean pool ----------------
__global__ __launch_bounds__(256) void k_pool(const float* __restrict__ x3,
                                              float* __restrict__ pooled) {
    int t = threadIdx.x, bb = blockIdx.x;
    float acc = 0.f;
    for (int n = bb; n < NN; n += gridDim.x)
        acc += x3[(size_t)n * HIDC + t];
    atomicAdd(&pooled[t], acc);
}

// ---------------- MLP head: 256 -> 128 (gelu exact) -> 1 ----------------
__global__ __launch_bounds__(128) void k_mlp(const float* __restrict__ pooled,
                                             const float* __restrict__ Wv1,
                                             const float* __restrict__ bv1,
                                             const float* __restrict__ Wv2,
                                             const float* __restrict__ bv2,
                                             float* __restrict__ out) {
    int j = threadIdx.x;
    float s = bv1[j];
    const float invn = 1.0f / (float)NN;
    for (int c = 0; c < HIDC; c++)
        s += (pooled[c] * invn) * Wv1[c * 128 + j];
    float g = 0.5f * s * (1.0f + erff(s * 0.70710678118654752f));
    float v = g * Wv2[j];
    __shared__ float red[128];
    red[j] = v;
    __syncthreads();
    for (int off = 64; off > 0; off >>= 1) {
        if (j < off) red[j] += red[j + off];
        __syncthreads();
    }
    if (j == 0) out[0] = red[0] + bv2[0];
}

extern "C" void kernel_launch(void* const* d_in, const int* in_sizes, int n_in,
                              void* d_out, int out_size, void* d_ws, size_t ws_size,
                              hipStream_t stream) {
    const float* x_in  = (const float*)d_in[0];
    const int*   ei    = (const int*)d_in[1];
    // d_in[2] = edge_attr: ignored (GATConv has no edge_dim)
    const float* W1    = (const float*)d_in[3];
    const float* asrc1 = (const float*)d_in[4];
    const float* adst1 = (const float*)d_in[5];
    const float* b1    = (const float*)d_in[6];
    const float* W2    = (const float*)d_in[7];
    const float* asrc2 = (const float*)d_in[8];
    const float* adst2 = (const float*)d_in[9];
    const float* b2    = (const float*)d_in[10];
    const float* Wv1   = (const float*)d_in[11];
    const float* bv1   = (const float*)d_in[12];
    const float* Wv2   = (const float*)d_in[13];
    const float* bv2   = (const float*)d_in[14];
    float* out = (float*)d_out;

    char* w = (char*)d_ws;
    auto alloc = [&](size_t bytes) { char* p = w; w += (bytes + 255) & ~(size_t)255; return p; };
    float* aggX   = (float*)alloc(sizeof(float) * (size_t)NN * NH * KP);  // 11.5 MB
    float* x2     = (float*)alloc(sizeof(float) * (size_t)NN * D1);       // 40.96 MB
    float* h2     = (float*)alloc(sizeof(float) * (size_t)NN * HIDC);     // 10.24 MB
    float* x3     = (float*)alloc(sizeof(float) * (size_t)NN * HIDC);     // 10.24 MB
    float* as1    = (float*)alloc(sizeof(float) * NN * NH);
    float* ad1    = (float*)alloc(sizeof(float) * NN * NH);
    float* as2    = (float*)alloc(sizeof(float) * NN);
    float* ad2    = (float*)alloc(sizeof(float) * NN);
    float* alpha1 = (float*)alloc(sizeof(float) * (size_t)NET * NH);      // 2.72 MB
    float* alpha2 = (float*)alloc(sizeof(float) * NET);                   // 0.68 MB
    float* was1   = (float*)alloc(sizeof(float) * NH * FIN);
    float* wad1   = (float*)alloc(sizeof(float) * NH * FIN);
    float* pooled = (float*)alloc(sizeof(float) * HIDC);
    int*   counts = (int*)alloc(sizeof(int) * NN);
    int*   indptr = (int*)alloc(sizeof(int) * (NN + 1));
    int*   cursor = (int*)alloc(sizeof(int) * NN);
    int*   ssrc   = (int*)alloc(sizeof(int) * NET);

    hipMemsetAsync(counts, 0, sizeof(int) * NN, stream);
    hipMemsetAsync(pooled, 0, sizeof(float) * HIDC, stream);

    const int EB = (NET + 255) / 256;
    k_hist<<<EB, 256, 0, stream>>>(ei, counts);
    k_scan<<<1, 1024, 0, stream>>>(counts, indptr, cursor);
    k_scatter<<<EB, 256, 0, stream>>>(ei, cursor, ssrc);

    // ---- layer 1 (h1 never materialized) ----
    k_prep1<<<FIN, 256, 0, stream>>>(W1, asrc1, adst1, was1, wad1);
    k_att_x<<<(NN + 63) / 64, 64, 0, stream>>>(x_in, was1, wad1, as1, ad1);
    k_edge_softmax<4><<<NN, 64, 0, stream>>>(indptr, ssrc, as1, ad1, alpha1);
    k_aggX<<<NN, 64, 0, stream>>>(indptr, ssrc, alpha1, x_in, aggX);
    {
        dim3 g((NN + 31) / 32, 2, 4);
        k_gemm_l1<<<g, 256, 0, stream>>>(aggX, W1, b1, x2);
    }

    // ---- layer 2 ----
    {
        dim3 g((NN + 31) / 32, 2);
        k_gemm2<<<g, 256, 0, stream>>>(x2, W2, h2);
    }
    k_att_h<<<NN, 256, 0, stream>>>(h2, asrc2, adst2, as2, ad2);
    k_edge_softmax<1><<<NN, 64, 0, stream>>>(indptr, ssrc, as2, ad2, alpha2);
    k_aggr2<<<NN, 256, 0, stream>>>(indptr, ssrc, alpha2, h2, b2, x3);

    k_pool<<<40, 256, 0, stream>>>(x3, pooled);
    k_mlp<<<1, 128, 0, stream>>>(pooled, Wv1, bv1, Wv2, bv2, out);
}

// Round 3
// 500.851 us; speedup vs baseline: 1.1445x; 1.1445x over previous
//
#include <hip/hip_runtime.h>
#include <math.h>

#define NN   10000          // nodes
#define NE   160000         // raw edges
#define NET  (NE + NN)      // edges + self loops = 170000
#define FIN  70
#define KP   72             // FIN padded to 16B multiple
#define HIDC 256
#define NH   4
#define D1   1024           // NH*HIDC
#define SLOPE 0.2f

// ---------------- CSR build ----------------
__global__ void k_hist(const int* __restrict__ ei, int* __restrict__ counts) {
    int e = blockIdx.x * 256 + threadIdx.x;
    if (e >= NET) return;
    int dst = (e < NE) ? ei[NE + e] : (e - NE);
    atomicAdd(&counts[dst], 1);
}

__global__ __launch_bounds__(1024) void k_scan(const int* __restrict__ counts,
                                               int* __restrict__ indptr,
                                               int* __restrict__ cursor) {
    __shared__ int ls[1024];
    int t = threadIdx.x;
    int c[10];
    int base = t * 10;
    int lsum = 0;
#pragma unroll
    for (int i = 0; i < 10; i++) {
        int j = base + i;
        c[i] = (j < NN) ? counts[j] : 0;
        lsum += c[i];
    }
    ls[t] = lsum;
    __syncthreads();
    for (int off = 1; off < 1024; off <<= 1) {
        int v = (t >= off) ? ls[t - off] : 0;
        __syncthreads();
        ls[t] += v;
        __syncthreads();
    }
    int excl = ls[t] - lsum;
#pragma unroll
    for (int i = 0; i < 10; i++) {
        int j = base + i;
        if (j < NN) { indptr[j] = excl; cursor[j] = excl; excl += c[i]; }
    }
    if (t == 1023) indptr[NN] = ls[1023];
}

__global__ void k_scatter(const int* __restrict__ ei, int* __restrict__ cursor,
                          int* __restrict__ ssrc) {
    int e = blockIdx.x * 256 + threadIdx.x;
    if (e >= NET) return;
    int src, dst;
    if (e < NE) { src = ei[e]; dst = ei[NE + e]; }
    else        { src = e - NE; dst = src; }
    int pos = atomicAdd(&cursor[dst], 1);
    ssrc[pos] = src;
}

// ---------------- precompute was1/wad1: was[h][k] = sum_c W1[k, h*256+c] * att_src1[h,c] ----------------
__global__ __launch_bounds__(256) void k_prep1(const float* __restrict__ W1,
                                               const float* __restrict__ asrc,
                                               const float* __restrict__ adst,
                                               float* __restrict__ was,
                                               float* __restrict__ wad) {
    int k = blockIdx.x, t = threadIdx.x;
    __shared__ float rs[256], rd[256];
#pragma unroll
    for (int h = 0; h < NH; h++) {
        float wv = W1[(size_t)k * D1 + h * 256 + t];
        rs[t] = wv * asrc[h * 256 + t];
        rd[t] = wv * adst[h * 256 + t];
        __syncthreads();
        for (int off = 128; off > 0; off >>= 1) {
            if (t < off) { rs[t] += rs[t + off]; rd[t] += rd[t + off]; }
            __syncthreads();
        }
        if (t == 0) { was[h * FIN + k] = rs[0]; wad[h * FIN + k] = rd[0]; }
        __syncthreads();
    }
}

// ---------------- per-node attention logits from x: as1[n][h] = x[n] . was[h] ----------------
__global__ __launch_bounds__(64) void k_att_x(const float* __restrict__ x,
                                              const float* __restrict__ was,
                                              const float* __restrict__ wad,
                                              float* __restrict__ asn,
                                              float* __restrict__ adn) {
    __shared__ float xs[64][71];
    int t = threadIdx.x;
    int n0 = blockIdx.x * 64;
    for (int i = t; i < 64 * FIN; i += 64) {
        int r = i / FIN, k = i % FIN;
        int n = n0 + r;
        xs[r][k] = (n < NN) ? x[(size_t)n * FIN + k] : 0.f;
    }
    __syncthreads();
    int n = n0 + t;
    if (n >= NN) return;
    float a[NH] = {}, d[NH] = {};
    for (int k = 0; k < FIN; k++) {
        float xv = xs[t][k];
#pragma unroll
        for (int h = 0; h < NH; h++) {
            a[h] += xv * was[h * FIN + k];
            d[h] += xv * wad[h * FIN + k];
        }
    }
#pragma unroll
    for (int h = 0; h < NH; h++) { asn[n * NH + h] = a[h]; adn[n * NH + h] = d[h]; }
}

// ---------------- per-node attention coefficients from a feature buffer (layer 2) ----------------
__global__ __launch_bounds__(256) void k_att_h(const float* __restrict__ hbuf,
                                               const float* __restrict__ asrc,
                                               const float* __restrict__ adst,
                                               float* __restrict__ asn,
                                               float* __restrict__ adn) {
    int n = blockIdx.x, t = threadIdx.x;
    __shared__ float rs[256], rd[256];
    float v = hbuf[(size_t)n * HIDC + t];
    rs[t] = v * asrc[t];
    rd[t] = v * adst[t];
    __syncthreads();
    for (int off = 128; off > 0; off >>= 1) {
        if (t < off) { rs[t] += rs[t + off]; rd[t] += rd[t + off]; }
        __syncthreads();
    }
    if (t == 0) { asn[n] = rs[0]; adn[n] = rd[0]; }
}

// ---------------- per-dst-node segment softmax (1 wave/node) ----------------
template <int H>
__global__ __launch_bounds__(64) void k_edge_softmax(const int* __restrict__ indptr,
                                                     const int* __restrict__ ssrc,
                                                     const float* __restrict__ as,
                                                     const float* __restrict__ ad,
                                                     float* __restrict__ alpha) {
    int d = blockIdx.x;
    int lane = threadIdx.x;
    int beg = indptr[d], end = indptr[d + 1];
    float adv[H], m[H], sum[H];
#pragma unroll
    for (int h = 0; h < H; h++) { adv[h] = ad[d * H + h]; m[h] = -1e30f; sum[h] = 0.f; }
    for (int i = beg + lane; i < end; i += 64) {
        int s = ssrc[i];
#pragma unroll
        for (int h = 0; h < H; h++) {
            float e = as[s * H + h] + adv[h];
            e = (e > 0.f) ? e : SLOPE * e;
            m[h] = fmaxf(m[h], e);
        }
    }
#pragma unroll
    for (int h = 0; h < H; h++)
        for (int off = 32; off > 0; off >>= 1)
            m[h] = fmaxf(m[h], __shfl_xor(m[h], off));
    for (int i = beg + lane; i < end; i += 64) {
        int s = ssrc[i];
#pragma unroll
        for (int h = 0; h < H; h++) {
            float e = as[s * H + h] + adv[h];
            e = (e > 0.f) ? e : SLOPE * e;
            float ex = expf(e - m[h]);
            alpha[(size_t)i * H + h] = ex;
            sum[h] += ex;
        }
    }
#pragma unroll
    for (int h = 0; h < H; h++)
        for (int off = 32; off > 0; off >>= 1)
            sum[h] += __shfl_xor(sum[h], off);
    float inv[H];
#pragma unroll
    for (int h = 0; h < H; h++) inv[h] = 1.0f / (sum[h] + 1e-16f);
    for (int i = beg + lane; i < end; i += 64)
#pragma unroll
        for (int h = 0; h < H; h++)
            alpha[(size_t)i * H + h] *= inv[h];
}

// ---------------- layer-1 aggregation in INPUT space ----------------
__global__ __launch_bounds__(64) void k_aggX(const int* __restrict__ indptr,
                                             const int* __restrict__ ssrc,
                                             const float* __restrict__ alpha1,
                                             const float* __restrict__ x,
                                             float* __restrict__ aggX) {
    int d = blockIdx.x, t = threadIdx.x;
    int beg = indptr[d], end = indptr[d + 1];
    float ac[NH][2] = {};
    for (int i = beg; i < end; i++) {
        int s = ssrc[i];
        float4 al = *(const float4*)&alpha1[(size_t)i * 4];
        float xv0 = x[(size_t)s * FIN + t];
        float xv1 = (t < FIN - 64) ? x[(size_t)s * FIN + 64 + t] : 0.f;
        ac[0][0] += al.x * xv0; ac[0][1] += al.x * xv1;
        ac[1][0] += al.y * xv0; ac[1][1] += al.y * xv1;
        ac[2][0] += al.z * xv0; ac[2][1] += al.z * xv1;
        ac[3][0] += al.w * xv0; ac[3][1] += al.w * xv1;
    }
#pragma unroll
    for (int h = 0; h < NH; h++) {
        aggX[((size_t)d * NH + h) * KP + t] = ac[h][0];
        if (t < FIN - 64)      aggX[((size_t)d * NH + h) * KP + 64 + t] = ac[h][1];
        else if (t < KP - 64)  aggX[((size_t)d * NH + h) * KP + 64 + t] = 0.f;  // zero K-pad
    }
}

// ---------------- tiled fp32 GEMM, layer 1: x2[r][h*256+c] = relu(aggX[r,h,:]@W1[:,h*256+c] + b1) ----
// grid (79, 2, NH); block 256 (16x16); BM=128, BN=128, K=72 (BK=8); 8x8 per thread
__global__ __launch_bounds__(256) void k_gemm_l1(const float* __restrict__ aggX,
                                                 const float* __restrict__ W1,
                                                 const float* __restrict__ b1,
                                                 float* __restrict__ x2) {
    __shared__ float As[8][128];
    __shared__ float Bs[8][128];
    int t = threadIdx.x;
    int tx = t & 15, ty = t >> 4;
    int n0 = blockIdx.x * 128;
    int cb = blockIdx.y * 128;
    int h  = blockIdx.z;
    // staging indices
    int arow = t >> 1;                 // 0..127
    int ak   = (t & 1) * 4;            // 0 or 4
    int asr  = n0 + arow; if (asr >= NN) asr = NN - 1;
    const float* aptr = aggX + ((size_t)asr * NH + h) * KP;
    int bk = t >> 5;                   // 0..7
    int bc = (t & 31) * 4;             // 0..124
    float acc00[4][4] = {}, acc01[4][4] = {}, acc10[4][4] = {}, acc11[4][4] = {};
    for (int k0 = 0; k0 < KP; k0 += 8) {
        float4 av = *(const float4*)(aptr + k0 + ak);
        float4 bv = *(const float4*)(W1 + (size_t)(k0 + bk) * D1 + h * 256 + cb + bc);
        __syncthreads();
        As[ak + 0][arow] = av.x; As[ak + 1][arow] = av.y;
        As[ak + 2][arow] = av.z; As[ak + 3][arow] = av.w;
        *(float4*)&Bs[bk][bc] = bv;
        __syncthreads();
#pragma unroll
        for (int k = 0; k < 8; k++) {
            float4 a0 = *(const float4*)&As[k][ty * 4];
            float4 a1 = *(const float4*)&As[k][64 + ty * 4];
            float4 b0 = *(const float4*)&Bs[k][tx * 4];
            float4 b1v = *(const float4*)&Bs[k][64 + tx * 4];
            const float* ap0 = (const float*)&a0;
            const float* ap1 = (const float*)&a1;
            const float* bp0 = (const float*)&b0;
            const float* bp1 = (const float*)&b1v;
#pragma unroll
            for (int i = 0; i < 4; i++)
#pragma unroll
                for (int j = 0; j < 4; j++) {
                    acc00[i][j] += ap0[i] * bp0[j];
                    acc01[i][j] += ap0[i] * bp1[j];
                    acc10[i][j] += ap1[i] * bp0[j];
                    acc11[i][j] += ap1[i] * bp1[j];
                }
        }
    }
    float4 bb0 = *(const float4*)(b1 + h * 256 + cb + tx * 4);
    float4 bb1 = *(const float4*)(b1 + h * 256 + cb + 64 + tx * 4);
    const float* bbp0 = (const float*)&bb0;
    const float* bbp1 = (const float*)&bb1;
#pragma unroll
    for (int rh = 0; rh < 2; rh++)
#pragma unroll
        for (int i = 0; i < 4; i++) {
            int r = n0 + rh * 64 + ty * 4 + i;
            if (r >= NN) continue;
            float* op = x2 + (size_t)r * D1 + h * 256 + cb;
            float4 o0, o1;
            float (*aL)[4] = rh ? acc10 : acc00;
            float (*aR)[4] = rh ? acc11 : acc01;
            o0.x = fmaxf(aL[i][0] + bbp0[0], 0.f); o0.y = fmaxf(aL[i][1] + bbp0[1], 0.f);
            o0.z = fmaxf(aL[i][2] + bbp0[2], 0.f); o0.w = fmaxf(aL[i][3] + bbp0[3], 0.f);
            o1.x = fmaxf(aR[i][0] + bbp1[0], 0.f); o1.y = fmaxf(aR[i][1] + bbp1[1], 0.f);
            o1.z = fmaxf(aR[i][2] + bbp1[2], 0.f); o1.w = fmaxf(aR[i][3] + bbp1[3], 0.f);
            *(float4*)(op + tx * 4) = o0;
            *(float4*)(op + 64 + tx * 4) = o1;
        }
}

// ---------------- tiled fp32 GEMM, layer 2 (K-split 4, atomic accumulate) ----------------
// grid (79, 2, 4); block 256 (16x16); BM=128, BN=128, BK=16, Kslice=256
__global__ __launch_bounds__(256) void k_gemm2(const float* __restrict__ x2,
                                               const float* __restrict__ W2,
                                               float* __restrict__ h2) {
    __shared__ float As[16][128];
    __shared__ float Bs[16][128];
    int t = threadIdx.x;
    int tx = t & 15, ty = t >> 4;
    int n0 = blockIdx.x * 128;
    int cb = blockIdx.y * 128;
    int kbase = blockIdx.z * 256;
    int arow = t >> 1;                 // 0..127
    int ak   = (t & 1) * 8;            // 0 or 8
    int asr  = n0 + arow; if (asr >= NN) asr = NN - 1;
    const float* aptr = x2 + (size_t)asr * D1;
    int bk = t >> 4;                   // 0..15
    int bc = tx * 4;                   // 0..60
    float acc00[4][4] = {}, acc01[4][4] = {}, acc10[4][4] = {}, acc11[4][4] = {};
    for (int kc = 0; kc < 256; kc += 16) {
        int k0 = kbase + kc;
        float4 av0 = *(const float4*)(aptr + k0 + ak);
        float4 av1 = *(const float4*)(aptr + k0 + ak + 4);
        const float* wrow = W2 + (size_t)(k0 + bk) * HIDC + cb;
        float4 bv0 = *(const float4*)(wrow + bc);
        float4 bv1 = *(const float4*)(wrow + 64 + bc);
        __syncthreads();
        As[ak + 0][arow] = av0.x; As[ak + 1][arow] = av0.y;
        As[ak + 2][arow] = av0.z; As[ak + 3][arow] = av0.w;
        As[ak + 4][arow] = av1.x; As[ak + 5][arow] = av1.y;
        As[ak + 6][arow] = av1.z; As[ak + 7][arow] = av1.w;
        *(float4*)&Bs[bk][bc] = bv0;
        *(float4*)&Bs[bk][64 + bc] = bv1;
        __syncthreads();
#pragma unroll
        for (int k = 0; k < 16; k++) {
            float4 a0 = *(const float4*)&As[k][ty * 4];
            float4 a1 = *(const float4*)&As[k][64 + ty * 4];
            float4 b0 = *(const float4*)&Bs[k][tx * 4];
            float4 b1v = *(const float4*)&Bs[k][64 + tx * 4];
            const float* ap0 = (const float*)&a0;
            const float* ap1 = (const float*)&a1;
            const float* bp0 = (const float*)&b0;
            const float* bp1 = (const float*)&b1v;
#pragma unroll
            for (int i = 0; i < 4; i++)
#pragma unroll
                for (int j = 0; j < 4; j++) {
                    acc00[i][j] += ap0[i] * bp0[j];
                    acc01[i][j] += ap0[i] * bp1[j];
                    acc10[i][j] += ap1[i] * bp0[j];
                    acc11[i][j] += ap1[i] * bp1[j];
                }
        }
    }
#pragma unroll
    for (int rh = 0; rh < 2; rh++)
#pragma unroll
        for (int i = 0; i < 4; i++) {
            int r = n0 + rh * 64 + ty * 4 + i;
            if (r >= NN) continue;
            float* op = h2 + (size_t)r * HIDC + cb;
            float (*aL)[4] = rh ? acc10 : acc00;
            float (*aR)[4] = rh ? acc11 : acc01;
#pragma unroll
            for (int j = 0; j < 4; j++) {
                atomicAdd(op + tx * 4 + j, aL[i][j]);
                atomicAdd(op + 64 + tx * 4 + j, aR[i][j]);
            }
        }
}

// ---------------- layer-2 aggregation ----------------
__global__ __launch_bounds__(256) void k_aggr2(const int* __restrict__ indptr,
                                               const int* __restrict__ ssrc,
                                               const float* __restrict__ alpha,
                                               const float* __restrict__ h2,
                                               const float* __restrict__ b,
                                               float* __restrict__ x3) {
    int d = blockIdx.x, t = threadIdx.x;
    int beg = indptr[d], end = indptr[d + 1];
    float acc = 0.f;
    for (int i = beg; i < end; i++) {
        int s = ssrc[i];
        acc += alpha[i] * h2[(size_t)s * HIDC + t];
    }
    x3[(size_t)d * HIDC + t] = fmaxf(acc + b[t], 0.f);
}

// ---------------- mean pool ----------------
__global__ __launch_bounds__(256) void k_pool(const float* __restrict__ x3,
                                              float* __restrict__ pooled) {
    int t = threadIdx.x, bb = blockIdx.x;
    float acc = 0.f;
    for (int n = bb; n < NN; n += gridDim.x)
        acc += x3[(size_t)n * HIDC + t];
    atomicAdd(&pooled[t], acc);
}

// ---------------- MLP head: 256 -> 128 (gelu exact) -> 1 ----------------
__global__ __launch_bounds__(128) void k_mlp(const float* __restrict__ pooled,
                                             const float* __restrict__ Wv1,
                                             const float* __restrict__ bv1,
                                             const float* __restrict__ Wv2,
                                             const float* __restrict__ bv2,
                                             float* __restrict__ out) {
    int j = threadIdx.x;
    float s = bv1[j];
    const float invn = 1.0f / (float)NN;
    for (int c = 0; c < HIDC; c++)
        s += (pooled[c] * invn) * Wv1[c * 128 + j];
    float g = 0.5f * s * (1.0f + erff(s * 0.70710678118654752f));
    float v = g * Wv2[j];
    __shared__ float red[128];
    red[j] = v;
    __syncthreads();
    for (int off = 64; off > 0; off >>= 1) {
        if (j < off) red[j] += red[j + off];
        __syncthreads();
    }
    if (j == 0) out[0] = red[0] + bv2[0];
}

extern "C" void kernel_launch(void* const* d_in, const int* in_sizes, int n_in,
                              void* d_out, int out_size, void* d_ws, size_t ws_size,
                              hipStream_t stream) {
    const float* x_in  = (const float*)d_in[0];
    const int*   ei    = (const int*)d_in[1];
    // d_in[2] = edge_attr: ignored (GATConv has no edge_dim)
    const float* W1    = (const float*)d_in[3];
    const float* asrc1 = (const float*)d_in[4];
    const float* adst1 = (const float*)d_in[5];
    const float* b1    = (const float*)d_in[6];
    const float* W2    = (const float*)d_in[7];
    const float* asrc2 = (const float*)d_in[8];
    const float* adst2 = (const float*)d_in[9];
    const float* b2    = (const float*)d_in[10];
    const float* Wv1   = (const float*)d_in[11];
    const float* bv1   = (const float*)d_in[12];
    const float* Wv2   = (const float*)d_in[13];
    const float* bv2   = (const float*)d_in[14];
    float* out = (float*)d_out;

    char* w = (char*)d_ws;
    auto alloc = [&](size_t bytes) { char* p = w; w += (bytes + 255) & ~(size_t)255; return p; };
    float* aggX   = (float*)alloc(sizeof(float) * (size_t)NN * NH * KP);  // 11.5 MB
    float* x2     = (float*)alloc(sizeof(float) * (size_t)NN * D1);       // 40.96 MB
    float* h2     = (float*)alloc(sizeof(float) * (size_t)NN * HIDC);     // 10.24 MB
    float* x3     = (float*)alloc(sizeof(float) * (size_t)NN * HIDC);     // 10.24 MB
    float* as1    = (float*)alloc(sizeof(float) * NN * NH);
    float* ad1    = (float*)alloc(sizeof(float) * NN * NH);
    float* as2    = (float*)alloc(sizeof(float) * NN);
    float* ad2    = (float*)alloc(sizeof(float) * NN);
    float* alpha1 = (float*)alloc(sizeof(float) * (size_t)NET * NH);      // 2.72 MB
    float* alpha2 = (float*)alloc(sizeof(float) * NET);                   // 0.68 MB
    float* was1   = (float*)alloc(sizeof(float) * NH * FIN);
    float* wad1   = (float*)alloc(sizeof(float) * NH * FIN);
    float* pooled = (float*)alloc(sizeof(float) * HIDC);
    int*   counts = (int*)alloc(sizeof(int) * NN);
    int*   indptr = (int*)alloc(sizeof(int) * (NN + 1));
    int*   cursor = (int*)alloc(sizeof(int) * NN);
    int*   ssrc   = (int*)alloc(sizeof(int) * NET);

    hipMemsetAsync(counts, 0, sizeof(int) * NN, stream);
    hipMemsetAsync(pooled, 0, sizeof(float) * HIDC, stream);
    hipMemsetAsync(h2, 0, sizeof(float) * (size_t)NN * HIDC, stream);  // gemm2 accumulates

    const int EB = (NET + 255) / 256;
    k_hist<<<EB, 256, 0, stream>>>(ei, counts);
    k_scan<<<1, 1024, 0, stream>>>(counts, indptr, cursor);
    k_scatter<<<EB, 256, 0, stream>>>(ei, cursor, ssrc);

    // ---- layer 1 (h1 never materialized) ----
    k_prep1<<<FIN, 256, 0, stream>>>(W1, asrc1, adst1, was1, wad1);
    k_att_x<<<(NN + 63) / 64, 64, 0, stream>>>(x_in, was1, wad1, as1, ad1);
    k_edge_softmax<4><<<NN, 64, 0, stream>>>(indptr, ssrc, as1, ad1, alpha1);
    k_aggX<<<NN, 64, 0, stream>>>(indptr, ssrc, alpha1, x_in, aggX);
    {
        dim3 g((NN + 127) / 128, 2, NH);
        k_gemm_l1<<<g, 256, 0, stream>>>(aggX, W1, b1, x2);
    }

    // ---- layer 2 ----
    {
        dim3 g((NN + 127) / 128, 2, 4);   // z = K-split
        k_gemm2<<<g, 256, 0, stream>>>(x2, W2, h2);
    }
    k_att_h<<<NN, 256, 0, stream>>>(h2, asrc2, adst2, as2, ad2);
    k_edge_softmax<1><<<NN, 64, 0, stream>>>(indptr, ssrc, as2, ad2, alpha2);
    k_aggr2<<<NN, 256, 0, stream>>>(indptr, ssrc, alpha2, h2, b2, x3);

    k_pool<<<40, 256, 0, stream>>>(x3, pooled);
    k_mlp<<<1, 128, 0, stream>>>(pooled, Wv1, bv1, Wv2, bv2, out);
}

// Round 4
// 395.876 us; speedup vs baseline: 1.4480x; 1.2652x over previous
//
#include <hip/hip_runtime.h>
#include <math.h>

#define NN   10000          // nodes
#define NE   160000         // raw edges
#define NET  (NE + NN)      // edges + self loops = 170000
#define FIN  70
#define HIDC 256
#define NH   4
#define D1   1024           // NH*HIDC
#define SLOPE 0.2f
#define KL1  96             // per-segment K for layer-1 GEMM (72 padded to 96)

typedef float f32x4 __attribute__((ext_vector_type(4)));
typedef short bf16x8 __attribute__((ext_vector_type(8)));

__device__ __forceinline__ unsigned short f32_to_bf16(float f) {
    unsigned int u = __float_as_uint(f);
    unsigned int r = u + 0x7fffu + ((u >> 16) & 1u);   // round-to-nearest-even
    return (unsigned short)(r >> 16);
}
__device__ __forceinline__ float bf16_to_f32(unsigned short h) {
    return __uint_as_float(((unsigned int)h) << 16);
}

// ---------------- CSR build ----------------
__global__ void k_hist(const int* __restrict__ ei, int* __restrict__ counts) {
    int e = blockIdx.x * 256 + threadIdx.x;
    if (e >= NET) return;
    int dst = (e < NE) ? ei[NE + e] : (e - NE);
    atomicAdd(&counts[dst], 1);
}

__global__ __launch_bounds__(1024) void k_scan(const int* __restrict__ counts,
                                               int* __restrict__ indptr,
                                               int* __restrict__ cursor) {
    __shared__ int ls[1024];
    int t = threadIdx.x;
    int c[10];
    int base = t * 10;
    int lsum = 0;
#pragma unroll
    for (int i = 0; i < 10; i++) {
        int j = base + i;
        c[i] = (j < NN) ? counts[j] : 0;
        lsum += c[i];
    }
    ls[t] = lsum;
    __syncthreads();
    for (int off = 1; off < 1024; off <<= 1) {
        int v = (t >= off) ? ls[t - off] : 0;
        __syncthreads();
        ls[t] += v;
        __syncthreads();
    }
    int excl = ls[t] - lsum;
#pragma unroll
    for (int i = 0; i < 10; i++) {
        int j = base + i;
        if (j < NN) { indptr[j] = excl; cursor[j] = excl; excl += c[i]; }
    }
    if (t == 1023) indptr[NN] = ls[1023];
}

__global__ void k_scatter(const int* __restrict__ ei, int* __restrict__ cursor,
                          int* __restrict__ ssrc) {
    int e = blockIdx.x * 256 + threadIdx.x;
    if (e >= NET) return;
    int src, dst;
    if (e < NE) { src = ei[e]; dst = ei[NE + e]; }
    else        { src = e - NE; dst = src; }
    int pos = atomicAdd(&cursor[dst], 1);
    ssrc[pos] = src;
}

// ---------------- weight conversion: W2 [1024x256] -> W2t [n=256][k'=3072] bf16, segs {hi,hi,lo} ----
__global__ __launch_bounds__(256) void k_conv_w2(const float* __restrict__ W2,
                                                 unsigned short* __restrict__ W2t) {
    int kk = blockIdx.x;            // 0..1023
    int n  = threadIdx.x;           // 0..255
    float w = W2[(size_t)kk * HIDC + n];
    unsigned short hi = f32_to_bf16(w);
    unsigned short lo = f32_to_bf16(w - bf16_to_f32(hi));
    size_t base = (size_t)n * 3072;
    W2t[base + kk]        = hi;
    W2t[base + 1024 + kk] = hi;
    W2t[base + 2048 + kk] = lo;
}

// ---------------- W1 [70x1024] -> W1t [h][n=256][k'=288] bf16, segs {hi,hi,lo}, zero K-pad ----
__global__ __launch_bounds__(256) void k_conv_w1(const float* __restrict__ W1,
                                                 unsigned short* __restrict__ W1t) {
    int kk = blockIdx.x;            // 0..95
    int n  = threadIdx.x;           // 0..255
#pragma unroll
    for (int h = 0; h < NH; h++) {
        float w = (kk < FIN) ? W1[(size_t)kk * D1 + h * 256 + n] : 0.f;
        unsigned short hi = f32_to_bf16(w);
        unsigned short lo = f32_to_bf16(w - bf16_to_f32(hi));
        size_t base = ((size_t)(h * 256 + n)) * (3 * KL1);
        W1t[base + kk]           = hi;
        W1t[base + KL1 + kk]     = hi;
        W1t[base + 2 * KL1 + kk] = lo;
    }
}

// ---------------- precompute was1/wad1 ----------------
__global__ __launch_bounds__(256) void k_prep1(const float* __restrict__ W1,
                                               const float* __restrict__ asrc,
                                               const float* __restrict__ adst,
                                               float* __restrict__ was,
                                               float* __restrict__ wad) {
    int k = blockIdx.x, t = threadIdx.x;
    __shared__ float rs[256], rd[256];
#pragma unroll
    for (int h = 0; h < NH; h++) {
        float wv = W1[(size_t)k * D1 + h * 256 + t];
        rs[t] = wv * asrc[h * 256 + t];
        rd[t] = wv * adst[h * 256 + t];
        __syncthreads();
        for (int off = 128; off > 0; off >>= 1) {
            if (t < off) { rs[t] += rs[t + off]; rd[t] += rd[t + off]; }
            __syncthreads();
        }
        if (t == 0) { was[h * FIN + k] = rs[0]; wad[h * FIN + k] = rd[0]; }
        __syncthreads();
    }
}

// ---------------- per-node attention logits from x ----------------
__global__ __launch_bounds__(64) void k_att_x(const float* __restrict__ x,
                                              const float* __restrict__ was,
                                              const float* __restrict__ wad,
                                              float* __restrict__ asn,
                                              float* __restrict__ adn) {
    __shared__ float xs[64][71];
    int t = threadIdx.x;
    int n0 = blockIdx.x * 64;
    for (int i = t; i < 64 * FIN; i += 64) {
        int r = i / FIN, k = i % FIN;
        int n = n0 + r;
        xs[r][k] = (n < NN) ? x[(size_t)n * FIN + k] : 0.f;
    }
    __syncthreads();
    int n = n0 + t;
    if (n >= NN) return;
    float a[NH] = {}, d[NH] = {};
    for (int k = 0; k < FIN; k++) {
        float xv = xs[t][k];
#pragma unroll
        for (int h = 0; h < NH; h++) {
            a[h] += xv * was[h * FIN + k];
            d[h] += xv * wad[h * FIN + k];
        }
    }
#pragma unroll
    for (int h = 0; h < NH; h++) { asn[n * NH + h] = a[h]; adn[n * NH + h] = d[h]; }
}

// ---------------- per-dst-node segment softmax (1 wave/node) ----------------
template <int H>
__global__ __launch_bounds__(64) void k_edge_softmax(const int* __restrict__ indptr,
                                                     const int* __restrict__ ssrc,
                                                     const float* __restrict__ as,
                                                     const float* __restrict__ ad,
                                                     float* __restrict__ alpha) {
    int d = blockIdx.x;
    int lane = threadIdx.x;
    int beg = indptr[d], end = indptr[d + 1];
    float adv[H], m[H], sum[H];
#pragma unroll
    for (int h = 0; h < H; h++) { adv[h] = ad[d * H + h]; m[h] = -1e30f; sum[h] = 0.f; }
    for (int i = beg + lane; i < end; i += 64) {
        int s = ssrc[i];
#pragma unroll
        for (int h = 0; h < H; h++) {
            float e = as[s * H + h] + adv[h];
            e = (e > 0.f) ? e : SLOPE * e;
            m[h] = fmaxf(m[h], e);
        }
    }
#pragma unroll
    for (int h = 0; h < H; h++)
        for (int off = 32; off > 0; off >>= 1)
            m[h] = fmaxf(m[h], __shfl_xor(m[h], off));
    for (int i = beg + lane; i < end; i += 64) {
        int s = ssrc[i];
#pragma unroll
        for (int h = 0; h < H; h++) {
            float e = as[s * H + h] + adv[h];
            e = (e > 0.f) ? e : SLOPE * e;
            float ex = expf(e - m[h]);
            alpha[(size_t)i * H + h] = ex;
            sum[h] += ex;
        }
    }
#pragma unroll
    for (int h = 0; h < H; h++)
        for (int off = 32; off > 0; off >>= 1)
            sum[h] += __shfl_xor(sum[h], off);
    float inv[H];
#pragma unroll
    for (int h = 0; h < H; h++) inv[h] = 1.0f / (sum[h] + 1e-16f);
    for (int i = beg + lane; i < end; i += 64)
#pragma unroll
        for (int h = 0; h < H; h++)
            alpha[(size_t)i * H + h] *= inv[h];
}

// ---------------- layer-1 aggregation in INPUT space -> bf16 hi/lo [d][h][96] ----------------
__global__ __launch_bounds__(64) void k_aggX(const int* __restrict__ indptr,
                                             const int* __restrict__ ssrc,
                                             const float* __restrict__ alpha1,
                                             const float* __restrict__ x,
                                             unsigned short* __restrict__ aggXhi,
                                             unsigned short* __restrict__ aggXlo) {
    int d = blockIdx.x, t = threadIdx.x;
    int beg = indptr[d], end = indptr[d + 1];
    float ac[NH][2] = {};
    for (int i = beg; i < end; i++) {
        int s = ssrc[i];
        float4 al = *(const float4*)&alpha1[(size_t)i * 4];
        float xv0 = x[(size_t)s * FIN + t];
        float xv1 = (t < FIN - 64) ? x[(size_t)s * FIN + 64 + t] : 0.f;
        ac[0][0] += al.x * xv0; ac[0][1] += al.x * xv1;
        ac[1][0] += al.y * xv0; ac[1][1] += al.y * xv1;
        ac[2][0] += al.z * xv0; ac[2][1] += al.z * xv1;
        ac[3][0] += al.w * xv0; ac[3][1] += al.w * xv1;
    }
#pragma unroll
    for (int h = 0; h < NH; h++) {
        size_t base = ((size_t)d * NH + h) * KL1;
        float v0 = ac[h][0];
        unsigned short h0 = f32_to_bf16(v0);
        aggXhi[base + t] = h0;
        aggXlo[base + t] = f32_to_bf16(v0 - bf16_to_f32(h0));
        if (t < 32) {  // k in [64,96): data for t<6, zero pad for 6<=t<32
            float v1 = (t < FIN - 64) ? ac[h][1] : 0.f;
            unsigned short h1 = f32_to_bf16(v1);
            aggXhi[base + 64 + t] = h1;
            aggXlo[base + 64 + t] = f32_to_bf16(v1 - bf16_to_f32(h1));
        }
    }
}

// ---------------- MFMA GEMM layer 1: x2 = relu(aggX' @ W1t' + b1), K'=288 per head ----------------
// grid (79, 2, NH); 256 thr; BM=BN=128, BK=32; outputs bf16 hi/lo x2 [NN][1024]
__global__ __launch_bounds__(256) void k_gemm_l1(const unsigned short* __restrict__ aggXhi,
                                                 const unsigned short* __restrict__ aggXlo,
                                                 const unsigned short* __restrict__ W1t,
                                                 const float* __restrict__ b1,
                                                 unsigned short* __restrict__ x2hi,
                                                 unsigned short* __restrict__ x2lo) {
    __shared__ unsigned short As[128 * 40];
    __shared__ unsigned short Bs[128 * 40];
    int t = threadIdx.x;
    int n0 = blockIdx.x * 128;
    int cb = blockIdx.y * 128;       // col within head's 256
    int h  = blockIdx.z;
    int lane = t & 63, wave = t >> 6, quad = lane >> 4, l16 = lane & 15;
    int wr = (wave & 1) * 64, wc = (wave >> 1) * 64;
    int r0 = t >> 2, o0 = t & 3;                 // piece 0: rows 0..63
    int r1 = (t + 256) >> 2, o1 = t & 3;         // piece 1: rows 64..127
    int ar0 = (n0 + r0 < NN) ? n0 + r0 : NN - 1;
    int ar1 = (n0 + r1 < NN) ? n0 + r1 : NN - 1;
    f32x4 acc[4][4] = {};
    for (int kc = 0; kc < 9; kc++) {
        int seg = kc / 3;
        int kk  = (kc - seg * 3) * 32;
        const unsigned short* Asrc = (seg == 1) ? aggXlo : aggXhi;
        uint4 av0 = *(const uint4*)(Asrc + ((size_t)ar0 * NH + h) * KL1 + kk + o0 * 8);
        uint4 av1 = *(const uint4*)(Asrc + ((size_t)ar1 * NH + h) * KL1 + kk + o1 * 8);
        uint4 bv0 = *(const uint4*)(W1t + ((size_t)(h * 256 + cb + r0)) * (3 * KL1) + kc * 32 + o0 * 8);
        uint4 bv1 = *(const uint4*)(W1t + ((size_t)(h * 256 + cb + r1)) * (3 * KL1) + kc * 32 + o1 * 8);
        __syncthreads();
        *(uint4*)&As[r0 * 40 + o0 * 8] = av0;
        *(uint4*)&As[r1 * 40 + o1 * 8] = av1;
        *(uint4*)&Bs[r0 * 40 + o0 * 8] = bv0;
        *(uint4*)&Bs[r1 * 40 + o1 * 8] = bv1;
        __syncthreads();
        bf16x8 af[4], bf[4];
#pragma unroll
        for (int i = 0; i < 4; i++) af[i] = *(const bf16x8*)&As[(wr + i * 16 + l16) * 40 + quad * 8];
#pragma unroll
        for (int j = 0; j < 4; j++) bf[j] = *(const bf16x8*)&Bs[(wc + j * 16 + l16) * 40 + quad * 8];
#pragma unroll
        for (int i = 0; i < 4; i++)
#pragma unroll
            for (int j = 0; j < 4; j++)
                acc[i][j] = __builtin_amdgcn_mfma_f32_16x16x32_bf16(af[i], bf[j], acc[i][j], 0, 0, 0);
    }
#pragma unroll
    for (int i = 0; i < 4; i++)
#pragma unroll
        for (int j = 0; j < 4; j++) {
            int colg = h * 256 + cb + wc + j * 16 + l16;
            float bb = b1[colg];
#pragma unroll
            for (int reg = 0; reg < 4; reg++) {
                int r = n0 + wr + i * 16 + quad * 4 + reg;
                if (r >= NN) continue;
                float v = fmaxf(acc[i][j][reg] + bb, 0.f);
                unsigned short hi = f32_to_bf16(v);
                x2hi[(size_t)r * D1 + colg] = hi;
                x2lo[(size_t)r * D1 + colg] = f32_to_bf16(v - bf16_to_f32(hi));
            }
        }
}

// ---------------- MFMA GEMM layer 2: h2 = x2' @ W2t', K'=3072, K-split 2 -> partials ----------------
// grid (79, 2, 2); 256 thr; BM=BN=128, BK=32
__global__ __launch_bounds__(256) void k_gemm2(const unsigned short* __restrict__ x2hi,
                                               const unsigned short* __restrict__ x2lo,
                                               const unsigned short* __restrict__ W2t,
                                               float* __restrict__ h2a,
                                               float* __restrict__ h2b) {
    __shared__ unsigned short As[128 * 40];
    __shared__ unsigned short Bs[128 * 40];
    int t = threadIdx.x;
    int n0 = blockIdx.x * 128;
    int cb = blockIdx.y * 128;
    int z  = blockIdx.z;
    float* outp = z ? h2b : h2a;
    int lane = t & 63, wave = t >> 6, quad = lane >> 4, l16 = lane & 15;
    int wr = (wave & 1) * 64, wc = (wave >> 1) * 64;
    int r0 = t >> 2, o0 = t & 3;
    int r1 = (t + 256) >> 2, o1 = t & 3;
    int ar0 = (n0 + r0 < NN) ? n0 + r0 : NN - 1;
    int ar1 = (n0 + r1 < NN) ? n0 + r1 : NN - 1;
    f32x4 acc[4][4] = {};
    for (int kc = z * 48; kc < z * 48 + 48; kc++) {
        int seg = kc >> 5;
        int kk  = (kc & 31) * 32;
        const unsigned short* Asrc = (seg == 1) ? x2lo : x2hi;
        uint4 av0 = *(const uint4*)(Asrc + (size_t)ar0 * D1 + kk + o0 * 8);
        uint4 av1 = *(const uint4*)(Asrc + (size_t)ar1 * D1 + kk + o1 * 8);
        uint4 bv0 = *(const uint4*)(W2t + (size_t)(cb + r0) * 3072 + kc * 32 + o0 * 8);
        uint4 bv1 = *(const uint4*)(W2t + (size_t)(cb + r1) * 3072 + kc * 32 + o1 * 8);
        __syncthreads();
        *(uint4*)&As[r0 * 40 + o0 * 8] = av0;
        *(uint4*)&As[r1 * 40 + o1 * 8] = av1;
        *(uint4*)&Bs[r0 * 40 + o0 * 8] = bv0;
        *(uint4*)&Bs[r1 * 40 + o1 * 8] = bv1;
        __syncthreads();
        bf16x8 af[4], bf[4];
#pragma unroll
        for (int i = 0; i < 4; i++) af[i] = *(const bf16x8*)&As[(wr + i * 16 + l16) * 40 + quad * 8];
#pragma unroll
        for (int j = 0; j < 4; j++) bf[j] = *(const bf16x8*)&Bs[(wc + j * 16 + l16) * 40 + quad * 8];
#pragma unroll
        for (int i = 0; i < 4; i++)
#pragma unroll
            for (int j = 0; j < 4; j++)
                acc[i][j] = __builtin_amdgcn_mfma_f32_16x16x32_bf16(af[i], bf[j], acc[i][j], 0, 0, 0);
    }
#pragma unroll
    for (int i = 0; i < 4; i++)
#pragma unroll
        for (int j = 0; j < 4; j++) {
            int c = cb + wc + j * 16 + l16;
#pragma unroll
            for (int reg = 0; reg < 4; reg++) {
                int r = n0 + wr + i * 16 + quad * 4 + reg;
                if (r >= NN) continue;
                outp[(size_t)r * HIDC + c] = acc[i][j][reg];
            }
        }
}

// ---------------- combine partials + layer-2 attention coefficients ----------------
__global__ __launch_bounds__(256) void k_att_h2(float* __restrict__ h2a,
                                                const float* __restrict__ h2b,
                                                const float* __restrict__ asrc,
                                                const float* __restrict__ adst,
                                                float* __restrict__ asn,
                                                float* __restrict__ adn) {
    int n = blockIdx.x, t = threadIdx.x;
    __shared__ float rs[256], rd[256];
    float v = h2a[(size_t)n * HIDC + t] + h2b[(size_t)n * HIDC + t];
    h2a[(size_t)n * HIDC + t] = v;
    rs[t] = v * asrc[t];
    rd[t] = v * adst[t];
    __syncthreads();
    for (int off = 128; off > 0; off >>= 1) {
        if (t < off) { rs[t] += rs[t + off]; rd[t] += rd[t + off]; }
        __syncthreads();
    }
    if (t == 0) { asn[n] = rs[0]; adn[n] = rd[0]; }
}

// ---------------- layer-2 aggregation ----------------
__global__ __launch_bounds__(256) void k_aggr2(const int* __restrict__ indptr,
                                               const int* __restrict__ ssrc,
                                               const float* __restrict__ alpha,
                                               const float* __restrict__ h2,
                                               const float* __restrict__ b,
                                               float* __restrict__ x3) {
    int d = blockIdx.x, t = threadIdx.x;
    int beg = indptr[d], end = indptr[d + 1];
    float acc = 0.f;
    for (int i = beg; i < end; i++) {
        int s = ssrc[i];
        acc += alpha[i] * h2[(size_t)s * HIDC + t];
    }
    x3[(size_t)d * HIDC + t] = fmaxf(acc + b[t], 0.f);
}

// ---------------- mean pool ----------------
__global__ __launch_bounds__(256) void k_pool(const float* __restrict__ x3,
                                              float* __restrict__ pooled) {
    int t = threadIdx.x, bb = blockIdx.x;
    float acc = 0.f;
    for (int n = bb; n < NN; n += gridDim.x)
        acc += x3[(size_t)n * HIDC + t];
    atomicAdd(&pooled[t], acc);
}

// ---------------- MLP head: 256 -> 128 (gelu exact) -> 1 ----------------
__global__ __launch_bounds__(128) void k_mlp(const float* __restrict__ pooled,
                                             const float* __restrict__ Wv1,
                                             const float* __restrict__ bv1,
                                             const float* __restrict__ Wv2,
                                             const float* __restrict__ bv2,
                                             float* __restrict__ out) {
    int j = threadIdx.x;
    float s = bv1[j];
    const float invn = 1.0f / (float)NN;
    for (int c = 0; c < HIDC; c++)
        s += (pooled[c] * invn) * Wv1[c * 128 + j];
    float g = 0.5f * s * (1.0f + erff(s * 0.70710678118654752f));
    float v = g * Wv2[j];
    __shared__ float red[128];
    red[j] = v;
    __syncthreads();
    for (int off = 64; off > 0; off >>= 1) {
        if (j < off) red[j] += red[j + off];
        __syncthreads();
    }
    if (j == 0) out[0] = red[0] + bv2[0];
}

extern "C" void kernel_launch(void* const* d_in, const int* in_sizes, int n_in,
                              void* d_out, int out_size, void* d_ws, size_t ws_size,
                              hipStream_t stream) {
    const float* x_in  = (const float*)d_in[0];
    const int*   ei    = (const int*)d_in[1];
    // d_in[2] = edge_attr: ignored (GATConv has no edge_dim)
    const float* W1    = (const float*)d_in[3];
    const float* asrc1 = (const float*)d_in[4];
    const float* adst1 = (const float*)d_in[5];
    const float* b1    = (const float*)d_in[6];
    const float* W2    = (const float*)d_in[7];
    const float* asrc2 = (const float*)d_in[8];
    const float* adst2 = (const float*)d_in[9];
    const float* b2    = (const float*)d_in[10];
    const float* Wv1   = (const float*)d_in[11];
    const float* bv1   = (const float*)d_in[12];
    const float* Wv2   = (const float*)d_in[13];
    const float* bv2   = (const float*)d_in[14];
    float* out = (float*)d_out;

    char* w = (char*)d_ws;
    auto alloc = [&](size_t bytes) { char* p = w; w += (bytes + 255) & ~(size_t)255; return p; };
    unsigned short* x2hi   = (unsigned short*)alloc(2ull * NN * D1);           // 20.5 MB
    unsigned short* x2lo   = (unsigned short*)alloc(2ull * NN * D1);           // 20.5 MB
    unsigned short* aggXhi = (unsigned short*)alloc(2ull * NN * NH * KL1);     // 7.7 MB
    unsigned short* aggXlo = (unsigned short*)alloc(2ull * NN * NH * KL1);     // 7.7 MB
    float* h2a    = (float*)alloc(4ull * NN * HIDC);                           // 10.24 MB (final h2)
    float* h2b    = (float*)alloc(4ull * NN * HIDC);                           // 10.24 MB (partial, then x3)
    float* x3     = h2b;                                                       // alias: h2b dead after k_att_h2
    unsigned short* W2t = (unsigned short*)alloc(2ull * 256 * 3072);           // 1.57 MB
    unsigned short* W1t = (unsigned short*)alloc(2ull * NH * 256 * 3 * KL1);   // 0.59 MB
    float* as1    = (float*)alloc(sizeof(float) * NN * NH);
    float* ad1    = (float*)alloc(sizeof(float) * NN * NH);
    float* as2    = (float*)alloc(sizeof(float) * NN);
    float* ad2    = (float*)alloc(sizeof(float) * NN);
    float* alpha1 = (float*)alloc(sizeof(float) * (size_t)NET * NH);           // 2.72 MB
    float* alpha2 = (float*)alloc(sizeof(float) * NET);                        // 0.68 MB
    float* was1   = (float*)alloc(sizeof(float) * NH * FIN);
    float* wad1   = (float*)alloc(sizeof(float) * NH * FIN);
    float* pooled = (float*)alloc(sizeof(float) * HIDC);
    int*   counts = (int*)alloc(sizeof(int) * NN);
    int*   indptr = (int*)alloc(sizeof(int) * (NN + 1));
    int*   cursor = (int*)alloc(sizeof(int) * NN);
    int*   ssrc   = (int*)alloc(sizeof(int) * NET);

    hipMemsetAsync(counts, 0, sizeof(int) * NN, stream);
    hipMemsetAsync(pooled, 0, sizeof(float) * HIDC, stream);

    const int EB = (NET + 255) / 256;
    k_hist<<<EB, 256, 0, stream>>>(ei, counts);
    k_scan<<<1, 1024, 0, stream>>>(counts, indptr, cursor);
    k_scatter<<<EB, 256, 0, stream>>>(ei, cursor, ssrc);

    // weight conversions (independent of graph work)
    k_conv_w2<<<1024, 256, 0, stream>>>(W2, W2t);
    k_conv_w1<<<KL1, 256, 0, stream>>>(W1, W1t);

    // ---- layer 1 (h1 never materialized; GEMM after aggregation) ----
    k_prep1<<<FIN, 256, 0, stream>>>(W1, asrc1, adst1, was1, wad1);
    k_att_x<<<(NN + 63) / 64, 64, 0, stream>>>(x_in, was1, wad1, as1, ad1);
    k_edge_softmax<4><<<NN, 64, 0, stream>>>(indptr, ssrc, as1, ad1, alpha1);
    k_aggX<<<NN, 64, 0, stream>>>(indptr, ssrc, alpha1, x_in, aggXhi, aggXlo);
    {
        dim3 g((NN + 127) / 128, 2, NH);
        k_gemm_l1<<<g, 256, 0, stream>>>(aggXhi, aggXlo, W1t, b1, x2hi, x2lo);
    }

    // ---- layer 2 ----
    {
        dim3 g((NN + 127) / 128, 2, 2);   // z = K-split into separate partials
        k_gemm2<<<g, 256, 0, stream>>>(x2hi, x2lo, W2t, h2a, h2b);
    }
    k_att_h2<<<NN, 256, 0, stream>>>(h2a, h2b, asrc2, adst2, as2, ad2);
    k_edge_softmax<1><<<NN, 64, 0, stream>>>(indptr, ssrc, as2, ad2, alpha2);
    k_aggr2<<<NN, 256, 0, stream>>>(indptr, ssrc, alpha2, h2a, b2, x3);

    k_pool<<<40, 256, 0, stream>>>(x3, pooled);
    k_mlp<<<1, 128, 0, stream>>>(pooled, Wv1, bv1, Wv2, bv2, out);
}

// Round 5
// 363.562 us; speedup vs baseline: 1.5767x; 1.0889x over previous
//
#include <hip/hip_runtime.h>
#include <math.h>

#define NN   10000          // nodes
#define NE   160000         // raw edges
#define NET  (NE + NN)      // edges + self loops = 170000
#define FIN  70
#define HIDC 256
#define NH   4
#define D1   1024           // NH*HIDC
#define SLOPE 0.2f
#define KL1  96             // per-segment K for layer-1 GEMM (72 padded to 96)

typedef float f32x4 __attribute__((ext_vector_type(4)));
typedef short bf16x8 __attribute__((ext_vector_type(8)));

__device__ __forceinline__ unsigned short f32_to_bf16(float f) {
    unsigned int u = __float_as_uint(f);
    unsigned int r = u + 0x7fffu + ((u >> 16) & 1u);   // round-to-nearest-even
    return (unsigned short)(r >> 16);
}
__device__ __forceinline__ float bf16_to_f32(unsigned short h) {
    return __uint_as_float(((unsigned int)h) << 16);
}

// ---------------- CSR build ----------------
__global__ void k_hist(const int* __restrict__ ei, int* __restrict__ counts) {
    int e = blockIdx.x * 256 + threadIdx.x;
    if (e >= NET) return;
    int dst = (e < NE) ? ei[NE + e] : (e - NE);
    atomicAdd(&counts[dst], 1);
}

__global__ __launch_bounds__(1024) void k_scan(const int* __restrict__ counts,
                                               int* __restrict__ indptr,
                                               int* __restrict__ cursor) {
    __shared__ int ls[1024];
    int t = threadIdx.x;
    int c[10];
    int base = t * 10;
    int lsum = 0;
#pragma unroll
    for (int i = 0; i < 10; i++) {
        int j = base + i;
        c[i] = (j < NN) ? counts[j] : 0;
        lsum += c[i];
    }
    ls[t] = lsum;
    __syncthreads();
    for (int off = 1; off < 1024; off <<= 1) {
        int v = (t >= off) ? ls[t - off] : 0;
        __syncthreads();
        ls[t] += v;
        __syncthreads();
    }
    int excl = ls[t] - lsum;
#pragma unroll
    for (int i = 0; i < 10; i++) {
        int j = base + i;
        if (j < NN) { indptr[j] = excl; cursor[j] = excl; excl += c[i]; }
    }
    if (t == 1023) indptr[NN] = ls[1023];
}

__global__ void k_scatter(const int* __restrict__ ei, int* __restrict__ cursor,
                          int* __restrict__ ssrc) {
    int e = blockIdx.x * 256 + threadIdx.x;
    if (e >= NET) return;
    int src, dst;
    if (e < NE) { src = ei[e]; dst = ei[NE + e]; }
    else        { src = e - NE; dst = src; }
    int pos = atomicAdd(&cursor[dst], 1);
    ssrc[pos] = src;
}

// ---------------- weight conversion: W2 [1024x256] -> W2t [n=256][k'=3072] bf16, segs {hi,hi,lo} ----
__global__ __launch_bounds__(256) void k_conv_w2(const float* __restrict__ W2,
                                                 unsigned short* __restrict__ W2t) {
    int kk = blockIdx.x;            // 0..1023
    int n  = threadIdx.x;           // 0..255
    float w = W2[(size_t)kk * HIDC + n];
    unsigned short hi = f32_to_bf16(w);
    unsigned short lo = f32_to_bf16(w - bf16_to_f32(hi));
    size_t base = (size_t)n * 3072;
    W2t[base + kk]        = hi;
    W2t[base + 1024 + kk] = hi;
    W2t[base + 2048 + kk] = lo;
}

// ---------------- W1 [70x1024] -> W1t [h][n=256][k'=288] bf16, segs {hi,hi,lo}, zero K-pad ----
__global__ __launch_bounds__(256) void k_conv_w1(const float* __restrict__ W1,
                                                 unsigned short* __restrict__ W1t) {
    int kk = blockIdx.x;            // 0..95
    int n  = threadIdx.x;           // 0..255
#pragma unroll
    for (int h = 0; h < NH; h++) {
        float w = (kk < FIN) ? W1[(size_t)kk * D1 + h * 256 + n] : 0.f;
        unsigned short hi = f32_to_bf16(w);
        unsigned short lo = f32_to_bf16(w - bf16_to_f32(hi));
        size_t base = ((size_t)(h * 256 + n)) * (3 * KL1);
        W1t[base + kk]           = hi;
        W1t[base + KL1 + kk]     = hi;
        W1t[base + 2 * KL1 + kk] = lo;
    }
}

// ---------------- precompute was1/wad1 ----------------
__global__ __launch_bounds__(256) void k_prep1(const float* __restrict__ W1,
                                               const float* __restrict__ asrc,
                                               const float* __restrict__ adst,
                                               float* __restrict__ was,
                                               float* __restrict__ wad) {
    int k = blockIdx.x, t = threadIdx.x;
    __shared__ float rs[256], rd[256];
#pragma unroll
    for (int h = 0; h < NH; h++) {
        float wv = W1[(size_t)k * D1 + h * 256 + t];
        rs[t] = wv * asrc[h * 256 + t];
        rd[t] = wv * adst[h * 256 + t];
        __syncthreads();
        for (int off = 128; off > 0; off >>= 1) {
            if (t < off) { rs[t] += rs[t + off]; rd[t] += rd[t + off]; }
            __syncthreads();
        }
        if (t == 0) { was[h * FIN + k] = rs[0]; wad[h * FIN + k] = rd[0]; }
        __syncthreads();
    }
}

// ---------------- per-node attention logits from x ----------------
__global__ __launch_bounds__(64) void k_att_x(const float* __restrict__ x,
                                              const float* __restrict__ was,
                                              const float* __restrict__ wad,
                                              float* __restrict__ asn,
                                              float* __restrict__ adn) {
    __shared__ float xs[64][71];
    int t = threadIdx.x;
    int n0 = blockIdx.x * 64;
    for (int i = t; i < 64 * FIN; i += 64) {
        int r = i / FIN, k = i % FIN;
        int n = n0 + r;
        xs[r][k] = (n < NN) ? x[(size_t)n * FIN + k] : 0.f;
    }
    __syncthreads();
    int n = n0 + t;
    if (n >= NN) return;
    float a[NH] = {}, d[NH] = {};
    for (int k = 0; k < FIN; k++) {
        float xv = xs[t][k];
#pragma unroll
        for (int h = 0; h < NH; h++) {
            a[h] += xv * was[h * FIN + k];
            d[h] += xv * wad[h * FIN + k];
        }
    }
#pragma unroll
    for (int h = 0; h < NH; h++) { asn[n * NH + h] = a[h]; adn[n * NH + h] = d[h]; }
}

// ---------------- per-dst-node segment softmax (1 wave/node) ----------------
template <int H>
__global__ __launch_bounds__(64) void k_edge_softmax(const int* __restrict__ indptr,
                                                     const int* __restrict__ ssrc,
                                                     const float* __restrict__ as,
                                                     const float* __restrict__ ad,
                                                     float* __restrict__ alpha) {
    int d = blockIdx.x;
    int lane = threadIdx.x;
    int beg = indptr[d], end = indptr[d + 1];
    float adv[H], m[H], sum[H];
#pragma unroll
    for (int h = 0; h < H; h++) { adv[h] = ad[d * H + h]; m[h] = -1e30f; sum[h] = 0.f; }
    for (int i = beg + lane; i < end; i += 64) {
        int s = ssrc[i];
#pragma unroll
        for (int h = 0; h < H; h++) {
            float e = as[s * H + h] + adv[h];
            e = (e > 0.f) ? e : SLOPE * e;
            m[h] = fmaxf(m[h], e);
        }
    }
#pragma unroll
    for (int h = 0; h < H; h++)
        for (int off = 32; off > 0; off >>= 1)
            m[h] = fmaxf(m[h], __shfl_xor(m[h], off));
    for (int i = beg + lane; i < end; i += 64) {
        int s = ssrc[i];
#pragma unroll
        for (int h = 0; h < H; h++) {
            float e = as[s * H + h] + adv[h];
            e = (e > 0.f) ? e : SLOPE * e;
            float ex = expf(e - m[h]);
            alpha[(size_t)i * H + h] = ex;
            sum[h] += ex;
        }
    }
#pragma unroll
    for (int h = 0; h < H; h++)
        for (int off = 32; off > 0; off >>= 1)
            sum[h] += __shfl_xor(sum[h], off);
    float inv[H];
#pragma unroll
    for (int h = 0; h < H; h++) inv[h] = 1.0f / (sum[h] + 1e-16f);
    for (int i = beg + lane; i < end; i += 64)
#pragma unroll
        for (int h = 0; h < H; h++)
            alpha[(size_t)i * H + h] *= inv[h];
}

// ---------------- layer-1 aggregation in INPUT space -> bf16 hi/lo [d][h][96] ----------------
__global__ __launch_bounds__(64) void k_aggX(const int* __restrict__ indptr,
                                             const int* __restrict__ ssrc,
                                             const float* __restrict__ alpha1,
                                             const float* __restrict__ x,
                                             unsigned short* __restrict__ aggXhi,
                                             unsigned short* __restrict__ aggXlo) {
    int d = blockIdx.x, t = threadIdx.x;
    int beg = indptr[d], end = indptr[d + 1];
    float ac[NH][2] = {};
    for (int i = beg; i < end; i++) {
        int s = ssrc[i];
        float4 al = *(const float4*)&alpha1[(size_t)i * 4];
        float xv0 = x[(size_t)s * FIN + t];
        float xv1 = (t < FIN - 64) ? x[(size_t)s * FIN + 64 + t] : 0.f;
        ac[0][0] += al.x * xv0; ac[0][1] += al.x * xv1;
        ac[1][0] += al.y * xv0; ac[1][1] += al.y * xv1;
        ac[2][0] += al.z * xv0; ac[2][1] += al.z * xv1;
        ac[3][0] += al.w * xv0; ac[3][1] += al.w * xv1;
    }
#pragma unroll
    for (int h = 0; h < NH; h++) {
        size_t base = ((size_t)d * NH + h) * KL1;
        float v0 = ac[h][0];
        unsigned short h0 = f32_to_bf16(v0);
        aggXhi[base + t] = h0;
        aggXlo[base + t] = f32_to_bf16(v0 - bf16_to_f32(h0));
        if (t < 32) {  // k in [64,96): data for t<6, zero pad for 6<=t<32
            float v1 = (t < FIN - 64) ? ac[h][1] : 0.f;
            unsigned short h1 = f32_to_bf16(v1);
            aggXhi[base + 64 + t] = h1;
            aggXlo[base + 64 + t] = f32_to_bf16(v1 - bf16_to_f32(h1));
        }
    }
}

// ---------------- MFMA GEMM layer 1: x2 = relu(aggX' @ W1t' + b1), K'=288 per head ----------------
// grid (79, 2, NH); 256 thr; BM=BN=128, BK=32; outputs bf16 hi/lo x2 [NN][1024]
__global__ __launch_bounds__(256) void k_gemm_l1(const unsigned short* __restrict__ aggXhi,
                                                 const unsigned short* __restrict__ aggXlo,
                                                 const unsigned short* __restrict__ W1t,
                                                 const float* __restrict__ b1,
                                                 unsigned short* __restrict__ x2hi,
                                                 unsigned short* __restrict__ x2lo) {
    __shared__ unsigned short As[128 * 40];
    __shared__ unsigned short Bs[128 * 40];
    int t = threadIdx.x;
    int n0 = blockIdx.x * 128;
    int cb = blockIdx.y * 128;       // col within head's 256
    int h  = blockIdx.z;
    int lane = t & 63, wave = t >> 6, quad = lane >> 4, l16 = lane & 15;
    int wr = (wave & 1) * 64, wc = (wave >> 1) * 64;
    int r0 = t >> 2, o0 = t & 3;                 // piece 0: rows 0..63
    int r1 = (t + 256) >> 2, o1 = t & 3;         // piece 1: rows 64..127
    int ar0 = (n0 + r0 < NN) ? n0 + r0 : NN - 1;
    int ar1 = (n0 + r1 < NN) ? n0 + r1 : NN - 1;
    f32x4 acc[4][4] = {};
    for (int kc = 0; kc < 9; kc++) {
        int seg = kc / 3;
        int kk  = (kc - seg * 3) * 32;
        const unsigned short* Asrc = (seg == 1) ? aggXlo : aggXhi;
        uint4 av0 = *(const uint4*)(Asrc + ((size_t)ar0 * NH + h) * KL1 + kk + o0 * 8);
        uint4 av1 = *(const uint4*)(Asrc + ((size_t)ar1 * NH + h) * KL1 + kk + o1 * 8);
        uint4 bv0 = *(const uint4*)(W1t + ((size_t)(h * 256 + cb + r0)) * (3 * KL1) + kc * 32 + o0 * 8);
        uint4 bv1 = *(const uint4*)(W1t + ((size_t)(h * 256 + cb + r1)) * (3 * KL1) + kc * 32 + o1 * 8);
        __syncthreads();
        *(uint4*)&As[r0 * 40 + o0 * 8] = av0;
        *(uint4*)&As[r1 * 40 + o1 * 8] = av1;
        *(uint4*)&Bs[r0 * 40 + o0 * 8] = bv0;
        *(uint4*)&Bs[r1 * 40 + o1 * 8] = bv1;
        __syncthreads();
        bf16x8 af[4], bf[4];
#pragma unroll
        for (int i = 0; i < 4; i++) af[i] = *(const bf16x8*)&As[(wr + i * 16 + l16) * 40 + quad * 8];
#pragma unroll
        for (int j = 0; j < 4; j++) bf[j] = *(const bf16x8*)&Bs[(wc + j * 16 + l16) * 40 + quad * 8];
#pragma unroll
        for (int i = 0; i < 4; i++)
#pragma unroll
            for (int j = 0; j < 4; j++)
                acc[i][j] = __builtin_amdgcn_mfma_f32_16x16x32_bf16(af[i], bf[j], acc[i][j], 0, 0, 0);
    }
#pragma unroll
    for (int i = 0; i < 4; i++)
#pragma unroll
        for (int j = 0; j < 4; j++) {
            int colg = h * 256 + cb + wc + j * 16 + l16;
            float bb = b1[colg];
#pragma unroll
            for (int reg = 0; reg < 4; reg++) {
                int r = n0 + wr + i * 16 + quad * 4 + reg;
                if (r >= NN) continue;
                float v = fmaxf(acc[i][j][reg] + bb, 0.f);
                unsigned short hi = f32_to_bf16(v);
                x2hi[(size_t)r * D1 + colg] = hi;
                x2lo[(size_t)r * D1 + colg] = f32_to_bf16(v - bf16_to_f32(hi));
            }
        }
}

// ---------------- MFMA GEMM layer 2: h2 = x2' @ W2t', K'=3072, K-split 2 -> partials ----------------
// grid (79, 2, 2); 256 thr; BM=BN=128, BK=32
__global__ __launch_bounds__(256) void k_gemm2(const unsigned short* __restrict__ x2hi,
                                               const unsigned short* __restrict__ x2lo,
                                               const unsigned short* __restrict__ W2t,
                                               float* __restrict__ h2a,
                                               float* __restrict__ h2b) {
    __shared__ unsigned short As[128 * 40];
    __shared__ unsigned short Bs[128 * 40];
    int t = threadIdx.x;
    int n0 = blockIdx.x * 128;
    int cb = blockIdx.y * 128;
    int z  = blockIdx.z;
    float* outp = z ? h2b : h2a;
    int lane = t & 63, wave = t >> 6, quad = lane >> 4, l16 = lane & 15;
    int wr = (wave & 1) * 64, wc = (wave >> 1) * 64;
    int r0 = t >> 2, o0 = t & 3;
    int r1 = (t + 256) >> 2, o1 = t & 3;
    int ar0 = (n0 + r0 < NN) ? n0 + r0 : NN - 1;
    int ar1 = (n0 + r1 < NN) ? n0 + r1 : NN - 1;
    f32x4 acc[4][4] = {};
    for (int kc = z * 48; kc < z * 48 + 48; kc++) {
        int seg = kc >> 5;
        int kk  = (kc & 31) * 32;
        const unsigned short* Asrc = (seg == 1) ? x2lo : x2hi;
        uint4 av0 = *(const uint4*)(Asrc + (size_t)ar0 * D1 + kk + o0 * 8);
        uint4 av1 = *(const uint4*)(Asrc + (size_t)ar1 * D1 + kk + o1 * 8);
        uint4 bv0 = *(const uint4*)(W2t + (size_t)(cb + r0) * 3072 + kc * 32 + o0 * 8);
        uint4 bv1 = *(const uint4*)(W2t + (size_t)(cb + r1) * 3072 + kc * 32 + o1 * 8);
        __syncthreads();
        *(uint4*)&As[r0 * 40 + o0 * 8] = av0;
        *(uint4*)&As[r1 * 40 + o1 * 8] = av1;
        *(uint4*)&Bs[r0 * 40 + o0 * 8] = bv0;
        *(uint4*)&Bs[r1 * 40 + o1 * 8] = bv1;
        __syncthreads();
        bf16x8 af[4], bf[4];
#pragma unroll
        for (int i = 0; i < 4; i++) af[i] = *(const bf16x8*)&As[(wr + i * 16 + l16) * 40 + quad * 8];
#pragma unroll
        for (int j = 0; j < 4; j++) bf[j] = *(const bf16x8*)&Bs[(wc + j * 16 + l16) * 40 + quad * 8];
#pragma unroll
        for (int i = 0; i < 4; i++)
#pragma unroll
            for (int j = 0; j < 4; j++)
                acc[i][j] = __builtin_amdgcn_mfma_f32_16x16x32_bf16(af[i], bf[j], acc[i][j], 0, 0, 0);
    }
#pragma unroll
    for (int i = 0; i < 4; i++)
#pragma unroll
        for (int j = 0; j < 4; j++) {
            int c = cb + wc + j * 16 + l16;
#pragma unroll
            for (int reg = 0; reg < 4; reg++) {
                int r = n0 + wr + i * 16 + quad * 4 + reg;
                if (r >= NN) continue;
                outp[(size_t)r * HIDC + c] = acc[i][j][reg];
            }
        }
}

// ---------------- combine partials + layer-2 attention coefficients ----------------
__global__ __launch_bounds__(256) void k_att_h2(float* __restrict__ h2a,
                                                const float* __restrict__ h2b,
                                                const float* __restrict__ asrc,
                                                const float* __restrict__ adst,
                                                float* __restrict__ asn,
                                                float* __restrict__ adn) {
    int n = blockIdx.x, t = threadIdx.x;
    __shared__ float rs[256], rd[256];
    float v = h2a[(size_t)n * HIDC + t] + h2b[(size_t)n * HIDC + t];
    h2a[(size_t)n * HIDC + t] = v;
    rs[t] = v * asrc[t];
    rd[t] = v * adst[t];
    __syncthreads();
    for (int off = 128; off > 0; off >>= 1) {
        if (t < off) { rs[t] += rs[t + off]; rd[t] += rd[t + off]; }
        __syncthreads();
    }
    if (t == 0) { asn[n] = rs[0]; adn[n] = rd[0]; }
}

// ---------------- layer-2 aggregation ----------------
__global__ __launch_bounds__(256) void k_aggr2(const int* __restrict__ indptr,
                                               const int* __restrict__ ssrc,
                                               const float* __restrict__ alpha,
                                               const float* __restrict__ h2,
                                               const float* __restrict__ b,
                                               float* __restrict__ x3) {
    int d = blockIdx.x, t = threadIdx.x;
    int beg = indptr[d], end = indptr[d + 1];
    float acc = 0.f;
    for (int i = beg; i < end; i++) {
        int s = ssrc[i];
        acc += alpha[i] * h2[(size_t)s * HIDC + t];
    }
    x3[(size_t)d * HIDC + t] = fmaxf(acc + b[t], 0.f);
}

// ---------------- mean pool: 313 blocks x 32 rows, float4 loads, LDS cross-reduce ----------------
// block=256: c4 = t&63 (float4 col), rq = t>>6 (row group); 8 rows per thread
__global__ __launch_bounds__(256) void k_pool(const float* __restrict__ x3,
                                              float* __restrict__ pooled) {
    int t = threadIdx.x;
    int c4 = t & 63;
    int rq = t >> 6;
    int n0 = blockIdx.x * 32;
    float4 acc = {0.f, 0.f, 0.f, 0.f};
    for (int r = rq; r < 32; r += 4) {
        int n = n0 + r;
        if (n < NN) {
            float4 v = *(const float4*)(x3 + (size_t)n * HIDC + c4 * 4);
            acc.x += v.x; acc.y += v.y; acc.z += v.z; acc.w += v.w;
        }
    }
    __shared__ float4 red[256];
    red[t] = acc;
    __syncthreads();
    if (rq == 0) {
        float4 a = red[c4], b = red[64 + c4], c = red[128 + c4], d = red[192 + c4];
        float sx = a.x + b.x + c.x + d.x;
        float sy = a.y + b.y + c.y + d.y;
        float sz = a.z + b.z + c.z + d.z;
        float sw = a.w + b.w + c.w + d.w;
        atomicAdd(&pooled[c4 * 4 + 0], sx);
        atomicAdd(&pooled[c4 * 4 + 1], sy);
        atomicAdd(&pooled[c4 * 4 + 2], sz);
        atomicAdd(&pooled[c4 * 4 + 3], sw);
    }
}

// ---------------- MLP head: 256 -> 128 (gelu exact) -> 1 ----------------
__global__ __launch_bounds__(128) void k_mlp(const float* __restrict__ pooled,
                                             const float* __restrict__ Wv1,
                                             const float* __restrict__ bv1,
                                             const float* __restrict__ Wv2,
                                             const float* __restrict__ bv2,
                                             float* __restrict__ out) {
    int j = threadIdx.x;
    float s = bv1[j];
    const float invn = 1.0f / (float)NN;
    for (int c = 0; c < HIDC; c++)
        s += (pooled[c] * invn) * Wv1[c * 128 + j];
    float g = 0.5f * s * (1.0f + erff(s * 0.70710678118654752f));
    float v = g * Wv2[j];
    __shared__ float red[128];
    red[j] = v;
    __syncthreads();
    for (int off = 64; off > 0; off >>= 1) {
        if (j < off) red[j] += red[j + off];
        __syncthreads();
    }
    if (j == 0) out[0] = red[0] + bv2[0];
}

extern "C" void kernel_launch(void* const* d_in, const int* in_sizes, int n_in,
                              void* d_out, int out_size, void* d_ws, size_t ws_size,
                              hipStream_t stream) {
    const float* x_in  = (const float*)d_in[0];
    const int*   ei    = (const int*)d_in[1];
    // d_in[2] = edge_attr: ignored (GATConv has no edge_dim)
    const float* W1    = (const float*)d_in[3];
    const float* asrc1 = (const float*)d_in[4];
    const float* adst1 = (const float*)d_in[5];
    const float* b1    = (const float*)d_in[6];
    const float* W2    = (const float*)d_in[7];
    const float* asrc2 = (const float*)d_in[8];
    const float* adst2 = (const float*)d_in[9];
    const float* b2    = (const float*)d_in[10];
    const float* Wv1   = (const float*)d_in[11];
    const float* bv1   = (const float*)d_in[12];
    const float* Wv2   = (const float*)d_in[13];
    const float* bv2   = (const float*)d_in[14];
    float* out = (float*)d_out;

    char* w = (char*)d_ws;
    auto alloc = [&](size_t bytes) { char* p = w; w += (bytes + 255) & ~(size_t)255; return p; };
    unsigned short* x2hi   = (unsigned short*)alloc(2ull * NN * D1);           // 20.5 MB
    unsigned short* x2lo   = (unsigned short*)alloc(2ull * NN * D1);           // 20.5 MB
    unsigned short* aggXhi = (unsigned short*)alloc(2ull * NN * NH * KL1);     // 7.7 MB
    unsigned short* aggXlo = (unsigned short*)alloc(2ull * NN * NH * KL1);     // 7.7 MB
    float* h2a    = (float*)alloc(4ull * NN * HIDC);                           // 10.24 MB (final h2)
    float* h2b    = (float*)alloc(4ull * NN * HIDC);                           // 10.24 MB (partial, then x3)
    float* x3     = h2b;                                                       // alias: h2b dead after k_att_h2
    unsigned short* W2t = (unsigned short*)alloc(2ull * 256 * 3072);           // 1.57 MB
    unsigned short* W1t = (unsigned short*)alloc(2ull * NH * 256 * 3 * KL1);   // 0.59 MB
    float* as1    = (float*)alloc(sizeof(float) * NN * NH);
    float* ad1    = (float*)alloc(sizeof(float) * NN * NH);
    float* as2    = (float*)alloc(sizeof(float) * NN);
    float* ad2    = (float*)alloc(sizeof(float) * NN);
    float* alpha1 = (float*)alloc(sizeof(float) * (size_t)NET * NH);           // 2.72 MB
    float* alpha2 = (float*)alloc(sizeof(float) * NET);                        // 0.68 MB
    float* was1   = (float*)alloc(sizeof(float) * NH * FIN);
    float* wad1   = (float*)alloc(sizeof(float) * NH * FIN);
    float* pooled = (float*)alloc(sizeof(float) * HIDC);
    int*   counts = (int*)alloc(sizeof(int) * NN);
    int*   indptr = (int*)alloc(sizeof(int) * (NN + 1));
    int*   cursor = (int*)alloc(sizeof(int) * NN);
    int*   ssrc   = (int*)alloc(sizeof(int) * NET);

    hipMemsetAsync(counts, 0, sizeof(int) * NN, stream);
    hipMemsetAsync(pooled, 0, sizeof(float) * HIDC, stream);

    const int EB = (NET + 255) / 256;
    k_hist<<<EB, 256, 0, stream>>>(ei, counts);
    k_scan<<<1, 1024, 0, stream>>>(counts, indptr, cursor);
    k_scatter<<<EB, 256, 0, stream>>>(ei, cursor, ssrc);

    // weight conversions (independent of graph work)
    k_conv_w2<<<1024, 256, 0, stream>>>(W2, W2t);
    k_conv_w1<<<KL1, 256, 0, stream>>>(W1, W1t);

    // ---- layer 1 (h1 never materialized; GEMM after aggregation) ----
    k_prep1<<<FIN, 256, 0, stream>>>(W1, asrc1, adst1, was1, wad1);
    k_att_x<<<(NN + 63) / 64, 64, 0, stream>>>(x_in, was1, wad1, as1, ad1);
    k_edge_softmax<4><<<NN, 64, 0, stream>>>(indptr, ssrc, as1, ad1, alpha1);
    k_aggX<<<NN, 64, 0, stream>>>(indptr, ssrc, alpha1, x_in, aggXhi, aggXlo);
    {
        dim3 g((NN + 127) / 128, 2, NH);
        k_gemm_l1<<<g, 256, 0, stream>>>(aggXhi, aggXlo, W1t, b1, x2hi, x2lo);
    }

    // ---- layer 2 ----
    {
        dim3 g((NN + 127) / 128, 2, 2);   // z = K-split into separate partials
        k_gemm2<<<g, 256, 0, stream>>>(x2hi, x2lo, W2t, h2a, h2b);
    }
    k_att_h2<<<NN, 256, 0, stream>>>(h2a, h2b, asrc2, adst2, as2, ad2);
    k_edge_softmax<1><<<NN, 64, 0, stream>>>(indptr, ssrc, as2, ad2, alpha2);
    k_aggr2<<<NN, 256, 0, stream>>>(indptr, ssrc, alpha2, h2a, b2, x3);

    k_pool<<<313, 256, 0, stream>>>(x3, pooled);
    k_mlp<<<1, 128, 0, stream>>>(pooled, Wv1, bv1, Wv2, bv2, out);
}